// Round 11
// baseline (120.957 us; speedup 1.0000x reference)
//
#include <hip/hip_runtime.h>

typedef __bf16 bf16;
typedef __bf16 bf16x4 __attribute__((ext_vector_type(4)));
typedef __bf16 bf16x8 __attribute__((ext_vector_type(8)));
typedef float f32x4 __attribute__((ext_vector_type(4)));

#define NTOK 32768
#define SCALE_F 0.17677669529663689f

// ============ K1: k/v proj (transposed) + exp(k) + ctx^T + S1, atomic-reduced ============
// grid (64, 8b), 256 thr, 8 contiguous subtiles of 64 tokens, static loop. (round-6 exact)
__global__ __launch_bounds__(256) void k1_ctx(const float* __restrict__ x,
    const float* __restrict__ wqkv, float* __restrict__ ctx, float* __restrict__ s1)
{
  const int b = blockIdx.y, chunk = blockIdx.x;
  const int t = threadIdx.x, w = t>>6, l = t&63, lr = l&15, lg = l>>4;
  __shared__ bf16 xT[64*72];    // [n][c]
  __shared__ bf16 ek[128*72];   // [k-ch][n]  exp(k)
  __shared__ bf16 vl[128*72];   // [v-ch][n]  v

  bf16x8 bw[4][2];
  #pragma unroll
  for (int ct=0;ct<4;ct++)
    #pragma unroll
    for (int ks=0;ks<2;ks++){
      const float* src = wqkv + (128 + w*64 + ct*16 + lr)*64 + ks*32 + lg*8;
      #pragma unroll
      for (int j=0;j<8;j++) bw[ct][ks][j] = (bf16)src[j];
    }
  bf16x8 ones;
  #pragma unroll
  for (int j=0;j<8;j++) ones[j] = (bf16)1.0f;

  f32x4 ctxa[2][2]; f32x4 s1a[2];
  #pragma unroll
  for (int i=0;i<2;i++){
    s1a[i] = f32x4{0.f,0.f,0.f,0.f};
    #pragma unroll
    for (int j=0;j<2;j++) ctxa[i][j] = f32x4{0.f,0.f,0.f,0.f};
  }
  const float* xb = x + (long)b*64*NTOK;
  bf16* dst = (w<2) ? ek : vl;
  const int chb = (w&1)*64;
  const bool isk = (w<2);
  const int sn = t&63, cg16 = (t>>6)*16;

  bf16x8 t0, t1;
  {
    const int n0 = chunk*512;
    #pragma unroll
    for (int i=0;i<8;i++) t0[i] = (bf16)xb[(long)(cg16+i)*NTOK + n0 + sn];
    #pragma unroll
    for (int i=0;i<8;i++) t1[i] = (bf16)xb[(long)(cg16+8+i)*NTOK + n0 + sn];
  }

  for (int s=0; s<8; s++) {
    *(bf16x8*)&xT[sn*72 + cg16]     = t0;
    *(bf16x8*)&xT[sn*72 + cg16 + 8] = t1;
    __syncthreads();
    if (s+1 < 8){
      const int n0 = chunk*512 + (s+1)*64;
      #pragma unroll
      for (int i=0;i<8;i++) t0[i] = (bf16)xb[(long)(cg16+i)*NTOK + n0 + sn];
      #pragma unroll
      for (int i=0;i<8;i++) t1[i] = (bf16)xb[(long)(cg16+8+i)*NTOK + n0 + sn];
    }
    f32x4 acc[4][4];
    #pragma unroll
    for (int rt=0;rt<4;rt++)
      #pragma unroll
      for (int ct=0;ct<4;ct++) acc[rt][ct] = f32x4{0.f,0.f,0.f,0.f};
    #pragma unroll
    for (int ks=0;ks<2;ks++){
      bf16x8 af[4];
      #pragma unroll
      for (int rt=0;rt<4;rt++)
        af[rt] = *(const bf16x8*)&xT[(rt*16+lr)*72 + ks*32 + lg*8];
      #pragma unroll
      for (int rt=0;rt<4;rt++)
        #pragma unroll
        for (int ct=0;ct<4;ct++)
          acc[rt][ct] = __builtin_amdgcn_mfma_f32_16x16x32_bf16(af[rt], bw[ct][ks], acc[rt][ct], 0,0,0);
    }
    #pragma unroll
    for (int ct=0;ct<4;ct++){
      const int row = chb + ct*16 + lr;
      #pragma unroll
      for (int rt=0;rt<4;rt++){
        bf16x4 p;
        #pragma unroll
        for (int ri=0;ri<4;ri++){
          const float v = acc[rt][ct][ri];
          p[ri] = isk ? (bf16)__expf(v) : (bf16)v;
        }
        *(bf16x4*)&dst[row*72 + rt*16 + lg*4] = p;
      }
    }
    __syncthreads();
    #pragma unroll
    for (int ks=0;ks<2;ks++){
      bf16x8 bd[2];
      #pragma unroll
      for (int cd=0;cd<2;cd++)
        bd[cd] = *(const bf16x8*)&ek[(w*32 + cd*16 + lr)*72 + ks*32 + lg*8];
      #pragma unroll
      for (int re=0;re<2;re++){
        bf16x8 a = *(const bf16x8*)&vl[(w*32 + re*16 + lr)*72 + ks*32 + lg*8];
        #pragma unroll
        for (int cd=0;cd<2;cd++)
          ctxa[re][cd] = __builtin_amdgcn_mfma_f32_16x16x32_bf16(a, bd[cd], ctxa[re][cd], 0,0,0);
      }
      #pragma unroll
      for (int cd=0;cd<2;cd++)
        s1a[cd] = __builtin_amdgcn_mfma_f32_16x16x32_bf16(ones, bd[cd], s1a[cd], 0,0,0);
    }
  }
  float* cp = ctx + ((long)b*4 + w)*1024;
  #pragma unroll
  for (int re=0;re<2;re++)
    #pragma unroll
    for (int cd=0;cd<2;cd++)
      #pragma unroll
      for (int ri=0;ri<4;ri++){
        const int e = re*16 + lg*4 + ri, d = cd*16 + lr;
        atomicAdd(&cp[e*32 + d], ctxa[re][cd][ri]);
      }
  if (lg==0){
    #pragma unroll
    for (int cd=0;cd<2;cd++)
      atomicAdd(&s1[(long)b*128 + w*32 + cd*16 + lr], s1a[cd][0]);
  }
}

// ============ K2: build W2 = SCALE*w_out*ctx^T/S1 ============
__global__ __launch_bounds__(256) void k2_w2(const float* __restrict__ ctx,
    const float* __restrict__ s1, const float* __restrict__ wout, bf16* __restrict__ W2)
{
  const int b = blockIdx.y, h = blockIdx.x, t = threadIdx.x;
  __shared__ float cs[1024];
  __shared__ float s1s[32];
  {
    f32x4 p4 = *(const f32x4*)(ctx + ((long)b*4 + h)*1024 + t*4);
    *(f32x4*)&cs[t*4] = p4;
  }
  if (t < 32) s1s[t] = s1[(long)b*128 + h*32 + t];
  __syncthreads();
  const int d = t & 31;
  const float rinv = SCALE_F / s1s[d];
  #pragma unroll
  for (int oi=0; oi<8; oi++){
    const int o = (t>>5)*8 + oi;
    float acc = 0.f;
    #pragma unroll
    for (int e=0;e<32;e++) acc += wout[o*128 + h*32 + e] * cs[e*32 + d];
    W2[((long)b*64 + o)*128 + h*32 + d] = (bf16)(acc * rinv);
  }
}

// ============ K3: q-proj + softmax_D + y = W2@qsm + b_out -> ybf, stats atomics ====
// grid (64, 8b), 256 thr, static 8-tile loop. W2 fragments in REGISTERS (64 VGPR,
// loaded once from global); xT/qs double-buffered -> 2 barriers/iter.
// __launch_bounds__(256,1): allow high VGPR, avoid round-7 spill-at-64 trap.
__global__ __launch_bounds__(256,1) void k3_y(const float* __restrict__ x,
    const float* __restrict__ wqkv, const bf16* __restrict__ W2g,
    const float* __restrict__ bout, bf16* __restrict__ ybf, float* __restrict__ yacc)
{
  const int b = blockIdx.y, blk = blockIdx.x;
  const int t = threadIdx.x, w = t>>6, l = t&63, lr = l&15, lg = l>>4;
  __shared__ bf16 xT[2][64*72];
  __shared__ bf16 qs[2][64*136];
  __shared__ float red[8];
  const float* xb = x + (long)b*64*NTOK;
  bf16* yb = ybf + (long)b*64*NTOK;

  bf16x8 qfr[2][2];   // q rows w*32 .. w*32+31
  #pragma unroll
  for (int rt=0;rt<2;rt++)
    #pragma unroll
    for (int ks=0;ks<2;ks++){
      const float* src = wqkv + (w*32 + rt*16 + lr)*64 + ks*32 + lg*8;
      #pragma unroll
      for (int j=0;j<8;j++) qfr[rt][ks][j] = (bf16)src[j];
    }
  // W2 A-fragments in registers, loaded once (same rows for every wave)
  bf16x8 wa[4][4];
  #pragma unroll
  for (int rt=0;rt<4;rt++)
    #pragma unroll
    for (int ks=0;ks<4;ks++)
      wa[rt][ks] = *(const bf16x8*)(W2g + (long)b*8192 + (rt*16+lr)*128 + ks*32 + lg*8);
  float boutr[16];
  #pragma unroll
  for (int rt=0;rt<4;rt++)
    #pragma unroll
    for (int ri=0;ri<4;ri++) boutr[rt*4+ri] = bout[rt*16 + lg*4 + ri];

  const int sn = t&63, cg16 = (t>>6)*16;
  bf16x8 t0, t1;
  {
    const int n0 = blk*512;
    #pragma unroll
    for (int i=0;i<8;i++) t0[i] = (bf16)xb[(long)(cg16+i)*NTOK + n0 + sn];
    #pragma unroll
    for (int i=0;i<8;i++) t1[i] = (bf16)xb[(long)(cg16+8+i)*NTOK + n0 + sn];
  }
  float sum=0.f, ss=0.f;

  #pragma unroll
  for (int ti=0; ti<8; ti++){
    const int p = ti & 1;
    const int n0 = blk*512 + ti*64;
    *(bf16x8*)&xT[p][sn*72 + cg16]     = t0;
    *(bf16x8*)&xT[p][sn*72 + cg16 + 8] = t1;
    __syncthreads();   // A: xT[p] ready
    if (ti+1 < 8){
      const int nn0 = n0 + 64;
      #pragma unroll
      for (int i=0;i<8;i++) t0[i] = (bf16)xb[(long)(cg16+i)*NTOK + nn0 + sn];
      #pragma unroll
      for (int i=0;i<8;i++) t1[i] = (bf16)xb[(long)(cg16+8+i)*NTOK + nn0 + sn];
    }
    f32x4 qa[2][4];
    #pragma unroll
    for (int rt=0;rt<2;rt++)
      #pragma unroll
      for (int ct=0;ct<4;ct++) qa[rt][ct] = f32x4{0.f,0.f,0.f,0.f};
    #pragma unroll
    for (int ks=0;ks<2;ks++){
      bf16x8 bfr[4];
      #pragma unroll
      for (int ct=0;ct<4;ct++)
        bfr[ct] = *(const bf16x8*)&xT[p][(ct*16+lr)*72 + ks*32 + lg*8];
      #pragma unroll
      for (int rt=0;rt<2;rt++)
        #pragma unroll
        for (int ct=0;ct<4;ct++)
          qa[rt][ct] = __builtin_amdgcn_mfma_f32_16x16x32_bf16(qfr[rt][ks], bfr[ct], qa[rt][ct], 0,0,0);
    }
    // per-head softmax over 32 head-dim rows per token col (correct, round-6 form)
    #pragma unroll
    for (int ct=0;ct<4;ct++){
      float e[2][4]; float pp = 0.f;
      #pragma unroll
      for (int rt=0;rt<2;rt++)
        #pragma unroll
        for (int ri=0;ri<4;ri++){ e[rt][ri] = __expf(qa[rt][ct][ri]); pp += e[rt][ri]; }
      pp += __shfl_xor(pp, 16, 64);
      pp += __shfl_xor(pp, 32, 64);
      const float rinv = 1.f/pp;
      const int nn = ct*16 + lr;
      #pragma unroll
      for (int rt=0;rt<2;rt++){
        bf16x4 pk;
        #pragma unroll
        for (int ri=0;ri<4;ri++) pk[ri] = (bf16)(e[rt][ri]*rinv);
        *(bf16x4*)&qs[p][nn*136 + w*32 + rt*16 + lg*4] = pk;
      }
    }
    __syncthreads();   // B: qs[p] ready
    f32x4 ya[4];
    #pragma unroll
    for (int rt=0;rt<4;rt++) ya[rt] = f32x4{0.f,0.f,0.f,0.f};
    #pragma unroll
    for (int ks=0;ks<4;ks++){
      bf16x8 bq = *(const bf16x8*)&qs[p][(w*16+lr)*136 + ks*32 + lg*8];
      #pragma unroll
      for (int rt=0;rt<4;rt++)
        ya[rt] = __builtin_amdgcn_mfma_f32_16x16x32_bf16(wa[rt][ks], bq, ya[rt], 0,0,0);
    }
    #pragma unroll
    for (int rt=0;rt<4;rt++)
      #pragma unroll
      for (int ri=0;ri<4;ri++){
        const int o = rt*16 + lg*4 + ri;
        const float val = ya[rt][ri] + boutr[rt*4+ri];
        sum += val; ss += val*val;
        yb[(long)o*NTOK + n0 + w*16 + lr] = (bf16)val;
      }
    // no tail barrier: double-buffered xT/qs make next-iter writes safe
  }
  #pragma unroll
  for (int off=1; off<64; off<<=1){
    sum += __shfl_xor(sum, off, 64);
    ss  += __shfl_xor(ss,  off, 64);
  }
  if (l==0){ red[w*2] = sum; red[w*2+1] = ss; }
  __syncthreads();
  if (t==0){
    atomicAdd(&yacc[b*2],   red[0]+red[2]+red[4]+red[6]);
    atomicAdd(&yacc[b*2+1], red[1]+red[3]+red[5]+red[7]);
  }
}

// ============ K4: normalize + affine, ybf16 -> out f32 (proven ~15us, BW roof) ========
__global__ __launch_bounds__(256) void k4_norm(const bf16* __restrict__ ybf,
    const float* __restrict__ yacc, const float* __restrict__ gamma,
    const float* __restrict__ beta, float* __restrict__ out)
{
  const long idx = ((long)blockIdx.x*256 + threadIdx.x)*8;
  const int b = (int)(idx >> 21);
  const int c = (int)((idx >> 15) & 63);
  const float inv_n = 1.f/2097152.f;
  const float mu  = yacc[b*2]*inv_n;
  const float inv = rsqrtf(yacc[b*2+1]*inv_n - mu*mu + 1e-5f);
  const float g = gamma[c]*inv;
  const float be = beta[c] - mu*g;
  bf16x8 v8 = *(const bf16x8*)(ybf + idx);
  f32x4 o0, o1;
  #pragma unroll
  for (int j=0;j<4;j++){ o0[j] = (float)v8[j]*g + be; o1[j] = (float)v8[4+j]*g + be; }
  *(f32x4*)(out + idx)     = o0;
  *(f32x4*)(out + idx + 4) = o1;
}

extern "C" void kernel_launch(void* const* d_in, const int* in_sizes, int n_in,
                              void* d_out, int out_size, void* d_ws, size_t ws_size,
                              hipStream_t stream) {
  const float* x     = (const float*)d_in[0];
  const float* wqkv  = (const float*)d_in[1];
  const float* wout  = (const float*)d_in[2];
  const float* bout  = (const float*)d_in[3];
  const float* gamma = (const float*)d_in[4];
  const float* beta  = (const float*)d_in[5];
  float* out = (float*)d_out;
  char* ws = (char*)d_ws;
  if (ws_size < 33820736u) return;  // ~33.8 MB

  float* ctx  = (float*)(ws + 0);        // [8][4][1024] f32 = 131072 B
  float* s1   = (float*)(ws + 131072);   // [8][128] f32     = 4096 B
  float* yacc = (float*)(ws + 135168);   // [8][2] f32       = 64 B
  bf16*  W2   = (bf16*) (ws + 135232);   // [8][64][128] bf16 = 131072 B
  bf16*  ybf  = (bf16*) (ws + 266304);   // [8][64][32768] bf16 = 33554432 B

  hipMemsetAsync(ws, 0, 135232, stream);  // zero ctx + s1 + yacc
  k1_ctx <<<dim3(64,8), 256, 0, stream>>>(x, wqkv, ctx, s1);
  k2_w2  <<<dim3(4,8),  256, 0, stream>>>(ctx, s1, wout, W2);
  k3_y   <<<dim3(64,8), 256, 0, stream>>>(x, wqkv, W2, bout, ybf, yacc);
  k4_norm<<<8192,       256, 0, stream>>>(ybf, yacc, gamma, beta, out);
}

// Round 12
// 115.125 us; speedup vs baseline: 1.0507x; 1.0507x over previous
//
#include <hip/hip_runtime.h>

typedef __bf16 bf16;
typedef __bf16 bf16x4 __attribute__((ext_vector_type(4)));
typedef __bf16 bf16x8 __attribute__((ext_vector_type(8)));
typedef float f32x4 __attribute__((ext_vector_type(4)));

#define NTOK 32768
#define SCALE_F 0.17677669529663689f

// ============ K1: k/v proj (transposed) + exp(k) + ctx^T + S1, atomic-reduced ============
// grid (128, 8b), 256 thr, 4 contiguous subtiles of 64 tokens, static loop.
// (round-6 body; only chunk size 512->256 for 4 blocks/CU residency)
__global__ __launch_bounds__(256) void k1_ctx(const float* __restrict__ x,
    const float* __restrict__ wqkv, float* __restrict__ ctx, float* __restrict__ s1)
{
  const int b = blockIdx.y, chunk = blockIdx.x;
  const int t = threadIdx.x, w = t>>6, l = t&63, lr = l&15, lg = l>>4;
  __shared__ bf16 xT[64*72];    // [n][c]
  __shared__ bf16 ek[128*72];   // [k-ch][n]  exp(k)
  __shared__ bf16 vl[128*72];   // [v-ch][n]  v

  bf16x8 bw[4][2];
  #pragma unroll
  for (int ct=0;ct<4;ct++)
    #pragma unroll
    for (int ks=0;ks<2;ks++){
      const float* src = wqkv + (128 + w*64 + ct*16 + lr)*64 + ks*32 + lg*8;
      #pragma unroll
      for (int j=0;j<8;j++) bw[ct][ks][j] = (bf16)src[j];
    }
  bf16x8 ones;
  #pragma unroll
  for (int j=0;j<8;j++) ones[j] = (bf16)1.0f;

  f32x4 ctxa[2][2]; f32x4 s1a[2];
  #pragma unroll
  for (int i=0;i<2;i++){
    s1a[i] = f32x4{0.f,0.f,0.f,0.f};
    #pragma unroll
    for (int j=0;j<2;j++) ctxa[i][j] = f32x4{0.f,0.f,0.f,0.f};
  }
  const float* xb = x + (long)b*64*NTOK;
  bf16* dst = (w<2) ? ek : vl;
  const int chb = (w&1)*64;
  const bool isk = (w<2);
  const int sn = t&63, cg16 = (t>>6)*16;

  bf16x8 t0, t1;
  {
    const int n0 = chunk*256;
    #pragma unroll
    for (int i=0;i<8;i++) t0[i] = (bf16)xb[(long)(cg16+i)*NTOK + n0 + sn];
    #pragma unroll
    for (int i=0;i<8;i++) t1[i] = (bf16)xb[(long)(cg16+8+i)*NTOK + n0 + sn];
  }

  for (int s=0; s<4; s++) {
    *(bf16x8*)&xT[sn*72 + cg16]     = t0;
    *(bf16x8*)&xT[sn*72 + cg16 + 8] = t1;
    __syncthreads();
    if (s+1 < 4){
      const int n0 = chunk*256 + (s+1)*64;
      #pragma unroll
      for (int i=0;i<8;i++) t0[i] = (bf16)xb[(long)(cg16+i)*NTOK + n0 + sn];
      #pragma unroll
      for (int i=0;i<8;i++) t1[i] = (bf16)xb[(long)(cg16+8+i)*NTOK + n0 + sn];
    }
    f32x4 acc[4][4];
    #pragma unroll
    for (int rt=0;rt<4;rt++)
      #pragma unroll
      for (int ct=0;ct<4;ct++) acc[rt][ct] = f32x4{0.f,0.f,0.f,0.f};
    #pragma unroll
    for (int ks=0;ks<2;ks++){
      bf16x8 af[4];
      #pragma unroll
      for (int rt=0;rt<4;rt++)
        af[rt] = *(const bf16x8*)&xT[(rt*16+lr)*72 + ks*32 + lg*8];
      #pragma unroll
      for (int rt=0;rt<4;rt++)
        #pragma unroll
        for (int ct=0;ct<4;ct++)
          acc[rt][ct] = __builtin_amdgcn_mfma_f32_16x16x32_bf16(af[rt], bw[ct][ks], acc[rt][ct], 0,0,0);
    }
    #pragma unroll
    for (int ct=0;ct<4;ct++){
      const int row = chb + ct*16 + lr;
      #pragma unroll
      for (int rt=0;rt<4;rt++){
        bf16x4 p;
        #pragma unroll
        for (int ri=0;ri<4;ri++){
          const float v = acc[rt][ct][ri];
          p[ri] = isk ? (bf16)__expf(v) : (bf16)v;
        }
        *(bf16x4*)&dst[row*72 + rt*16 + lg*4] = p;
      }
    }
    __syncthreads();
    #pragma unroll
    for (int ks=0;ks<2;ks++){
      bf16x8 bd[2];
      #pragma unroll
      for (int cd=0;cd<2;cd++)
        bd[cd] = *(const bf16x8*)&ek[(w*32 + cd*16 + lr)*72 + ks*32 + lg*8];
      #pragma unroll
      for (int re=0;re<2;re++){
        bf16x8 a = *(const bf16x8*)&vl[(w*32 + re*16 + lr)*72 + ks*32 + lg*8];
        #pragma unroll
        for (int cd=0;cd<2;cd++)
          ctxa[re][cd] = __builtin_amdgcn_mfma_f32_16x16x32_bf16(a, bd[cd], ctxa[re][cd], 0,0,0);
      }
      #pragma unroll
      for (int cd=0;cd<2;cd++)
        s1a[cd] = __builtin_amdgcn_mfma_f32_16x16x32_bf16(ones, bd[cd], s1a[cd], 0,0,0);
    }
  }
  float* cp = ctx + ((long)b*4 + w)*1024;
  #pragma unroll
  for (int re=0;re<2;re++)
    #pragma unroll
    for (int cd=0;cd<2;cd++)
      #pragma unroll
      for (int ri=0;ri<4;ri++){
        const int e = re*16 + lg*4 + ri, d = cd*16 + lr;
        atomicAdd(&cp[e*32 + d], ctxa[re][cd][ri]);
      }
  if (lg==0){
    #pragma unroll
    for (int cd=0;cd<2;cd++)
      atomicAdd(&s1[(long)b*128 + w*32 + cd*16 + lr], s1a[cd][0]);
  }
}

// ============ K2: build W2 = SCALE*w_out*ctx^T/S1 ============
__global__ __launch_bounds__(256) void k2_w2(const float* __restrict__ ctx,
    const float* __restrict__ s1, const float* __restrict__ wout, bf16* __restrict__ W2)
{
  const int b = blockIdx.y, h = blockIdx.x, t = threadIdx.x;
  __shared__ float cs[1024];
  __shared__ float s1s[32];
  {
    f32x4 p4 = *(const f32x4*)(ctx + ((long)b*4 + h)*1024 + t*4);
    *(f32x4*)&cs[t*4] = p4;
  }
  if (t < 32) s1s[t] = s1[(long)b*128 + h*32 + t];
  __syncthreads();
  const int d = t & 31;
  const float rinv = SCALE_F / s1s[d];
  #pragma unroll
  for (int oi=0; oi<8; oi++){
    const int o = (t>>5)*8 + oi;
    float acc = 0.f;
    #pragma unroll
    for (int e=0;e<32;e++) acc += wout[o*128 + h*32 + e] * cs[e*32 + d];
    W2[((long)b*64 + o)*128 + h*32 + d] = (bf16)(acc * rinv);
  }
}

// ============ K3: q-proj + softmax_D + y = W2@qsm + b_out -> ybf, stats atomics ====
// grid (128, 8b), 256 thr, 4 token-tiles per block (round-4 proven shape ~25us).
// W2s in LDS, 3 barriers/iter, native bf16 casts, bf16 y stores.
#define K3T 4
__global__ __launch_bounds__(256,2) void k3_y(const float* __restrict__ x,
    const float* __restrict__ wqkv, const bf16* __restrict__ W2g,
    const float* __restrict__ bout, bf16* __restrict__ ybf, float* __restrict__ yacc)
{
  const int b = blockIdx.y, blk = blockIdx.x;
  const int t = threadIdx.x, w = t>>6, l = t&63, lr = l&15, lg = l>>4;
  __shared__ bf16 W2s[64*136];
  __shared__ bf16 xT[64*72];
  __shared__ bf16 qs[64*136];
  __shared__ float red[8];
  const float* xb = x + (long)b*64*NTOK;
  bf16* yb = ybf + (long)b*64*NTOK;

  bf16x8 qfr[2][2];   // q rows w*32 .. w*32+31
  #pragma unroll
  for (int rt=0;rt<2;rt++)
    #pragma unroll
    for (int ks=0;ks<2;ks++){
      const float* src = wqkv + (w*32 + rt*16 + lr)*64 + ks*32 + lg*8;
      #pragma unroll
      for (int j=0;j<8;j++) qfr[rt][ks][j] = (bf16)src[j];
    }
  { // stage W2[b] -> LDS once per block
    const bf16* src = W2g + (long)b*8192 + t*32;
    const int o = t>>2, c0 = (t&3)*32;
    #pragma unroll
    for (int k=0;k<4;k++)
      *(bf16x8*)&W2s[o*136 + c0 + k*8] = *(const bf16x8*)(src + k*8);
  }
  float boutr[16];
  #pragma unroll
  for (int rt=0;rt<4;rt++)
    #pragma unroll
    for (int ri=0;ri<4;ri++) boutr[rt*4+ri] = bout[rt*16 + lg*4 + ri];

  const int sn = t&63, cg16 = (t>>6)*16;
  bf16x8 t0, t1;
  { // prologue: prefetch tile 0
    const int n0 = blk*K3T*64;
    #pragma unroll
    for (int i=0;i<8;i++) t0[i] = (bf16)xb[(long)(cg16+i)*NTOK + n0 + sn];
    #pragma unroll
    for (int i=0;i<8;i++) t1[i] = (bf16)xb[(long)(cg16+8+i)*NTOK + n0 + sn];
  }
  float sum=0.f, ss=0.f;

  #pragma unroll
  for (int ti=0; ti<K3T; ti++){
    const int n0 = (blk*K3T + ti)*64;
    *(bf16x8*)&xT[sn*72 + cg16]     = t0;
    *(bf16x8*)&xT[sn*72 + cg16 + 8] = t1;
    __syncthreads();   // xT ready (also W2s on ti=0)
    if (ti+1 < K3T){
      const int nn0 = n0 + 64;
      #pragma unroll
      for (int i=0;i<8;i++) t0[i] = (bf16)xb[(long)(cg16+i)*NTOK + nn0 + sn];
      #pragma unroll
      for (int i=0;i<8;i++) t1[i] = (bf16)xb[(long)(cg16+8+i)*NTOK + nn0 + sn];
    }
    f32x4 qa[2][4];
    #pragma unroll
    for (int rt=0;rt<2;rt++)
      #pragma unroll
      for (int ct=0;ct<4;ct++) qa[rt][ct] = f32x4{0.f,0.f,0.f,0.f};
    #pragma unroll
    for (int ks=0;ks<2;ks++){
      bf16x8 bfr[4];
      #pragma unroll
      for (int ct=0;ct<4;ct++)
        bfr[ct] = *(const bf16x8*)&xT[(ct*16+lr)*72 + ks*32 + lg*8];
      #pragma unroll
      for (int rt=0;rt<2;rt++)
        #pragma unroll
        for (int ct=0;ct<4;ct++)
          qa[rt][ct] = __builtin_amdgcn_mfma_f32_16x16x32_bf16(qfr[rt][ks], bfr[ct], qa[rt][ct], 0,0,0);
    }
    // per-head softmax over 32 head-dim rows per token col
    #pragma unroll
    for (int ct=0;ct<4;ct++){
      float e[2][4]; float p = 0.f;
      #pragma unroll
      for (int rt=0;rt<2;rt++)
        #pragma unroll
        for (int ri=0;ri<4;ri++){ e[rt][ri] = __expf(qa[rt][ct][ri]); p += e[rt][ri]; }
      p += __shfl_xor(p, 16, 64);
      p += __shfl_xor(p, 32, 64);
      const float rinv = 1.f/p;
      const int nn = ct*16 + lr;
      #pragma unroll
      for (int rt=0;rt<2;rt++){
        bf16x4 pk;
        #pragma unroll
        for (int ri=0;ri<4;ri++) pk[ri] = (bf16)(e[rt][ri]*rinv);
        *(bf16x4*)&qs[nn*136 + w*32 + rt*16 + lg*4] = pk;
      }
    }
    __syncthreads();   // qs ready
    f32x4 ya[4];
    #pragma unroll
    for (int rt=0;rt<4;rt++) ya[rt] = f32x4{0.f,0.f,0.f,0.f};
    #pragma unroll
    for (int ks=0;ks<4;ks++){
      bf16x8 bq = *(const bf16x8*)&qs[(w*16+lr)*136 + ks*32 + lg*8];
      #pragma unroll
      for (int rt=0;rt<4;rt++){
        bf16x8 a = *(const bf16x8*)&W2s[(rt*16+lr)*136 + ks*32 + lg*8];
        ya[rt] = __builtin_amdgcn_mfma_f32_16x16x32_bf16(a, bq, ya[rt], 0,0,0);
      }
    }
    #pragma unroll
    for (int rt=0;rt<4;rt++)
      #pragma unroll
      for (int ri=0;ri<4;ri++){
        const int o = rt*16 + lg*4 + ri;
        const float val = ya[rt][ri] + boutr[rt*4+ri];
        sum += val; ss += val*val;
        yb[(long)o*NTOK + n0 + w*16 + lr] = (bf16)val;
      }
    __syncthreads();   // PV reads done before next iter's xT/qs writes
  }
  #pragma unroll
  for (int off=1; off<64; off<<=1){
    sum += __shfl_xor(sum, off, 64);
    ss  += __shfl_xor(ss,  off, 64);
  }
  if (l==0){ red[w*2] = sum; red[w*2+1] = ss; }
  __syncthreads();
  if (t==0){
    atomicAdd(&yacc[b*2],   red[0]+red[2]+red[4]+red[6]);
    atomicAdd(&yacc[b*2+1], red[1]+red[3]+red[5]+red[7]);
  }
}

// ============ K4: normalize + affine, ybf16 -> out f32 (proven ~15us, BW roof) ========
__global__ __launch_bounds__(256) void k4_norm(const bf16* __restrict__ ybf,
    const float* __restrict__ yacc, const float* __restrict__ gamma,
    const float* __restrict__ beta, float* __restrict__ out)
{
  const long idx = ((long)blockIdx.x*256 + threadIdx.x)*8;
  const int b = (int)(idx >> 21);
  const int c = (int)((idx >> 15) & 63);
  const float inv_n = 1.f/2097152.f;
  const float mu  = yacc[b*2]*inv_n;
  const float inv = rsqrtf(yacc[b*2+1]*inv_n - mu*mu + 1e-5f);
  const float g = gamma[c]*inv;
  const float be = beta[c] - mu*g;
  bf16x8 v8 = *(const bf16x8*)(ybf + idx);
  f32x4 o0, o1;
  #pragma unroll
  for (int j=0;j<4;j++){ o0[j] = (float)v8[j]*g + be; o1[j] = (float)v8[4+j]*g + be; }
  *(f32x4*)(out + idx)     = o0;
  *(f32x4*)(out + idx + 4) = o1;
}

extern "C" void kernel_launch(void* const* d_in, const int* in_sizes, int n_in,
                              void* d_out, int out_size, void* d_ws, size_t ws_size,
                              hipStream_t stream) {
  const float* x     = (const float*)d_in[0];
  const float* wqkv  = (const float*)d_in[1];
  const float* wout  = (const float*)d_in[2];
  const float* bout  = (const float*)d_in[3];
  const float* gamma = (const float*)d_in[4];
  const float* beta  = (const float*)d_in[5];
  float* out = (float*)d_out;
  char* ws = (char*)d_ws;
  if (ws_size < 33820736u) return;  // ~33.8 MB

  float* ctx  = (float*)(ws + 0);        // [8][4][1024] f32 = 131072 B
  float* s1   = (float*)(ws + 131072);   // [8][128] f32     = 4096 B
  float* yacc = (float*)(ws + 135168);   // [8][2] f32       = 64 B
  bf16*  W2   = (bf16*) (ws + 135232);   // [8][64][128] bf16 = 131072 B
  bf16*  ybf  = (bf16*) (ws + 266304);   // [8][64][32768] bf16 = 33554432 B

  hipMemsetAsync(ws, 0, 135232, stream);  // zero ctx + s1 + yacc
  k1_ctx <<<dim3(128,8), 256, 0, stream>>>(x, wqkv, ctx, s1);
  k2_w2  <<<dim3(4,8),   256, 0, stream>>>(ctx, s1, wout, W2);
  k3_y   <<<dim3(128,8), 256, 0, stream>>>(x, wqkv, W2, bout, ybf, yacc);
  k4_norm<<<8192,        256, 0, stream>>>(ybf, yacc, gamma, beta, out);
}